// Round 1
// baseline (1806.160 us; speedup 1.0000x reference)
//
#include <hip/hip_runtime.h>

#define DIM 64

// ---------------- degree count (once; layer-invariant) ----------------
__global__ void deg_kernel(const int* __restrict__ dst, float* __restrict__ deg, int E) {
    int tid = blockIdx.x * blockDim.x + threadIdx.x;
    int stride = gridDim.x * blockDim.x;
    for (int e = tid; e < E; e += stride)
        atomicAdd(&deg[dst[e]], 1.0f);
}

// ---------------- hp = relu(h @ Wp^T + bp) ----------------
// one wave (64 lanes) per row; lane d computes output element d.
// Wp staged transposed in LDS: WpT[k][d] = Wp[d*64+k] -> lane reads stride-1 (conflict-free).
__global__ void proj_kernel(const float* __restrict__ h,
                            const float* __restrict__ Wp,
                            const float* __restrict__ bp,
                            float* __restrict__ hp, int n)
{
    __shared__ float WpT[DIM][DIM];
    __shared__ float bsh[DIM];
    int tid = threadIdx.x;
    for (int i = tid; i < DIM * DIM; i += 256) {
        int d = i / DIM, k = i % DIM;
        WpT[k][d] = Wp[i];
    }
    if (tid < DIM) bsh[tid] = bp[tid];
    __syncthreads();
    int wave = tid >> 6, lane = tid & 63;
    for (int base = blockIdx.x * 4; base < n; base += gridDim.x * 4) {
        int r = base + wave;
        if (r >= n) continue;
        float hval = h[(size_t)r * DIM + lane];
        float acc = bsh[lane];
        #pragma unroll
        for (int k = 0; k < DIM; ++k) {
            float hb = __shfl(hval, k);   // compile-time k -> v_readlane broadcast
            acc += hb * WpT[k][lane];
        }
        hp[(size_t)r * DIM + lane] = fmaxf(acc, 0.0f);
    }
}

// ---------------- scatter: agg[dst] += hp[src] ----------------
// 16 threads per edge, each thread: float4 gather + 4 atomicAdds.
__global__ void scatter_kernel(const float* __restrict__ hp,
                               const int* __restrict__ src,
                               const int* __restrict__ dst,
                               float* __restrict__ agg, long long totalQuads)
{
    long long tid = (long long)blockIdx.x * blockDim.x + threadIdx.x;
    long long stride = (long long)gridDim.x * blockDim.x;
    for (long long t = tid; t < totalQuads; t += stride) {
        int e = (int)(t >> 4);
        int q = (int)(t & 15);
        int s = src[e], d = dst[e];
        const float4 v = *reinterpret_cast<const float4*>(hp + (size_t)s * DIM + q * 4);
        float* ap = agg + (size_t)d * DIM + q * 4;
        atomicAdd(ap + 0, v.x);
        atomicAdd(ap + 1, v.y);
        atomicAdd(ap + 2, v.z);
        atomicAdd(ap + 3, v.w);
    }
}

// ---------------- out = LN(agg/deg @ Wl^T + bl + h @ Wr^T) * gamma + beta ----------------
__global__ void combine_ln_kernel(const float* __restrict__ h,
                                  const float* __restrict__ agg,
                                  const float* __restrict__ deg,
                                  const float* __restrict__ Wl,
                                  const float* __restrict__ bl,
                                  const float* __restrict__ Wr,
                                  const float* __restrict__ gamma,
                                  const float* __restrict__ beta,
                                  float* __restrict__ out, int n)
{
    __shared__ float WlT[DIM][DIM];
    __shared__ float WrT[DIM][DIM];
    __shared__ float blsh[DIM], gsh[DIM], bsh[DIM];
    int tid = threadIdx.x;
    for (int i = tid; i < DIM * DIM; i += 256) {
        int d = i / DIM, k = i % DIM;
        WlT[k][d] = Wl[i];
        WrT[k][d] = Wr[i];
    }
    if (tid < DIM) { blsh[tid] = bl[tid]; gsh[tid] = gamma[tid]; bsh[tid] = beta[tid]; }
    __syncthreads();
    int wave = tid >> 6, lane = tid & 63;
    for (int base = blockIdx.x * 4; base < n; base += gridDim.x * 4) {
        int r = base + wave;
        if (r >= n) continue;
        float hv = h[(size_t)r * DIM + lane];
        float dg = fmaxf(deg[r], 1.0f);
        float av = agg[(size_t)r * DIM + lane] / dg;
        float acc = blsh[lane];
        #pragma unroll
        for (int k = 0; k < DIM; ++k) {
            float ab = __shfl(av, k);
            float hb = __shfl(hv, k);
            acc += ab * WlT[k][lane] + hb * WrT[k][lane];
        }
        // LayerNorm across the 64 lanes (biased variance, eps=1e-5)
        float mu = acc;
        #pragma unroll
        for (int off = 32; off > 0; off >>= 1) mu += __shfl_xor(mu, off);
        mu *= (1.0f / 64.0f);
        float d0 = acc - mu;
        float var = d0 * d0;
        #pragma unroll
        for (int off = 32; off > 0; off >>= 1) var += __shfl_xor(var, off);
        var *= (1.0f / 64.0f);
        float inv = rsqrtf(var + 1e-5f);
        out[(size_t)r * DIM + lane] = d0 * inv * gsh[lane] + bsh[lane];
    }
}

extern "C" void kernel_launch(void* const* d_in, const int* in_sizes, int n_in,
                              void* d_out, int out_size, void* d_ws, size_t ws_size,
                              hipStream_t stream)
{
    const float* x      = (const float*)d_in[0];
    const int*   ei     = (const int*)d_in[1];
    const float* W_proj = (const float*)d_in[2];
    const float* b_proj = (const float*)d_in[3];
    const float* W_l    = (const float*)d_in[4];
    const float* b_l    = (const float*)d_in[5];
    const float* W_r    = (const float*)d_in[6];
    const float* gamma  = (const float*)d_in[7];
    const float* beta   = (const float*)d_in[8];

    const int N = in_sizes[0] / DIM;
    const int E = in_sizes[1] / 2;
    const int L = in_sizes[2] / (DIM * DIM);

    const int* src  = ei;
    const int* dstp = ei + E;

    float* hp  = (float*)d_ws;
    float* agg = hp  + (size_t)N * DIM;
    float* h1  = agg + (size_t)N * DIM;
    float* deg = h1  + (size_t)N * DIM;

    hipMemsetAsync(deg, 0, (size_t)N * sizeof(float), stream);
    deg_kernel<<<2048, 256, 0, stream>>>(dstp, deg, E);

    const float* hin = x;
    for (int l = 0; l < L; ++l) {
        proj_kernel<<<2048, 256, 0, stream>>>(hin, W_proj + (size_t)l * DIM * DIM,
                                              b_proj + (size_t)l * DIM, hp, N);
        hipMemsetAsync(agg, 0, (size_t)N * DIM * sizeof(float), stream);
        scatter_kernel<<<4096, 256, 0, stream>>>(hp, src, dstp, agg, (long long)E * 16);
        float* outp = (l == L - 1) ? (float*)d_out : h1;
        combine_ln_kernel<<<2048, 256, 0, stream>>>(hin, agg, deg,
                                                    W_l + (size_t)l * DIM * DIM, b_l + (size_t)l * DIM,
                                                    W_r + (size_t)l * DIM * DIM,
                                                    gamma + (size_t)l * DIM, beta + (size_t)l * DIM,
                                                    outp, N);
        hin = h1;
    }
}

// Round 2
// 440.304 us; speedup vs baseline: 4.1021x; 4.1021x over previous
//
#include <hip/hip_runtime.h>

#define DIM 64

// ---------------- int degree histogram ----------------
__global__ void hist_kernel(const int* __restrict__ dst, int* __restrict__ deg, int E) {
    int tid = blockIdx.x * blockDim.x + threadIdx.x;
    int stride = gridDim.x * blockDim.x;
    for (int e = tid; e < E; e += stride)
        atomicAdd(&deg[dst[e]], 1);
}

// ---------------- scan stage A: per-block sums ----------------
__global__ void scanA_kernel(const int* __restrict__ deg, int* __restrict__ blockSums, int N) {
    __shared__ int tmp[256];
    int t = threadIdx.x;
    int i = blockIdx.x * 256 + t;
    int v = (i < N) ? deg[i] : 0;
    tmp[t] = v;
    __syncthreads();
    for (int off = 128; off > 0; off >>= 1) {
        if (t < off) tmp[t] += tmp[t + off];
        __syncthreads();
    }
    if (t == 0) blockSums[blockIdx.x] = tmp[0];
}

// ---------------- scan stage B: exclusive scan of block sums (1 block) ----------------
__global__ void scanB_kernel(int* __restrict__ blockSums, int nblocks) {
    __shared__ int tmp[256];
    __shared__ int carry;
    int t = threadIdx.x;
    if (t == 0) carry = 0;
    __syncthreads();
    for (int base = 0; base < nblocks; base += 256) {
        int idx = base + t;
        int v = (idx < nblocks) ? blockSums[idx] : 0;
        tmp[t] = v;
        __syncthreads();
        for (int off = 1; off < 256; off <<= 1) {
            int add = (t >= off) ? tmp[t - off] : 0;
            __syncthreads();
            tmp[t] += add;
            __syncthreads();
        }
        int incl = tmp[t];
        int excl = incl - v + carry;            // reads carry before update barrier
        if (idx < nblocks) blockSums[idx] = excl;
        int chunkTotal = tmp[255];
        __syncthreads();
        if (t == 0) carry += chunkTotal;
        __syncthreads();
    }
}

// ---------------- scan stage C: per-element exclusive offsets ----------------
__global__ void scanC_kernel(const int* __restrict__ deg, const int* __restrict__ blockOff,
                             int* __restrict__ row_start, int* __restrict__ cursor, int N) {
    __shared__ int tmp[256];
    int b = blockIdx.x, t = threadIdx.x;
    int i = b * 256 + t;
    int v = (i < N) ? deg[i] : 0;
    tmp[t] = v;
    __syncthreads();
    for (int off = 1; off < 256; off <<= 1) {
        int add = (t >= off) ? tmp[t - off] : 0;
        __syncthreads();
        tmp[t] += add;
        __syncthreads();
    }
    int excl = tmp[t] - v + blockOff[b];
    if (i < N) {
        row_start[i] = excl;
        cursor[i] = excl;
        if (i == N - 1) row_start[N] = excl + v;
    }
}

// ---------------- bucket fill: csr_src grouped by dst ----------------
__global__ void bucket_kernel(const int* __restrict__ src, const int* __restrict__ dst,
                              int* __restrict__ cursor, int* __restrict__ csr_src, int E) {
    int tid = blockIdx.x * blockDim.x + threadIdx.x;
    int stride = gridDim.x * blockDim.x;
    for (int e = tid; e < E; e += stride) {
        int p = atomicAdd(&cursor[dst[e]], 1);
        csr_src[p] = src[e];
    }
}

// ---------------- hp = relu(h @ Wp^T + bp) ----------------
__global__ void proj_kernel(const float* __restrict__ h,
                            const float* __restrict__ Wp,
                            const float* __restrict__ bp,
                            float* __restrict__ hp, int n)
{
    __shared__ float WpT[DIM][DIM + 1];
    __shared__ float bsh[DIM];
    int tid = threadIdx.x;
    for (int i = tid; i < DIM * DIM; i += 256) {
        int d = i / DIM, k = i % DIM;
        WpT[k][d] = Wp[i];
    }
    if (tid < DIM) bsh[tid] = bp[tid];
    __syncthreads();
    int wave = tid >> 6, lane = tid & 63;
    for (int base = blockIdx.x * 4; base < n; base += gridDim.x * 4) {
        int r = base + wave;
        if (r >= n) continue;
        float hval = h[(size_t)r * DIM + lane];
        float acc = bsh[lane];
        #pragma unroll
        for (int k = 0; k < DIM; ++k) {
            float hb = __shfl(hval, k);
            acc += hb * WpT[k][lane];
        }
        hp[(size_t)r * DIM + lane] = fmaxf(acc, 0.0f);
    }
}

// ---------------- fused: agg (CSR gather) -> combine -> LayerNorm ----------------
__global__ void agg_combine_ln_kernel(const float* __restrict__ h,
                                      const float* __restrict__ hp,
                                      const int* __restrict__ row_start,
                                      const int* __restrict__ csr_src,
                                      const float* __restrict__ Wl,
                                      const float* __restrict__ bl,
                                      const float* __restrict__ Wr,
                                      const float* __restrict__ gamma,
                                      const float* __restrict__ beta,
                                      float* __restrict__ out, int n)
{
    __shared__ float WlT[DIM][DIM + 1];
    __shared__ float WrT[DIM][DIM + 1];
    __shared__ float blsh[DIM], gsh[DIM], bsh[DIM];
    int tid = threadIdx.x;
    for (int i = tid; i < DIM * DIM; i += 256) {
        int d = i / DIM, k = i % DIM;
        WlT[k][d] = Wl[i];
        WrT[k][d] = Wr[i];
    }
    if (tid < DIM) { blsh[tid] = bl[tid]; gsh[tid] = gamma[tid]; bsh[tid] = beta[tid]; }
    __syncthreads();
    int wave = tid >> 6, lane = tid & 63;
    for (int base = blockIdx.x * 4; base < n; base += gridDim.x * 4) {
        int r = base + wave;
        if (r >= n) continue;
        int rs = row_start[r];
        int re = row_start[r + 1];
        // gather-aggregate hp rows of incoming neighbors (no atomics)
        float acc = 0.0f;
        int j = rs;
        for (; j + 4 <= re; j += 4) {
            int s0 = csr_src[j];
            int s1 = csr_src[j + 1];
            int s2 = csr_src[j + 2];
            int s3 = csr_src[j + 3];
            float a0 = hp[(size_t)s0 * DIM + lane];
            float a1 = hp[(size_t)s1 * DIM + lane];
            float a2 = hp[(size_t)s2 * DIM + lane];
            float a3 = hp[(size_t)s3 * DIM + lane];
            acc += a0; acc += a1; acc += a2; acc += a3;
        }
        for (; j < re; ++j)
            acc += hp[(size_t)csr_src[j] * DIM + lane];
        float dg = (float)((re - rs) > 1 ? (re - rs) : 1);
        float av = acc / dg;
        float hv = h[(size_t)r * DIM + lane];
        float o = blsh[lane];
        #pragma unroll
        for (int k = 0; k < DIM; ++k) {
            float ab = __shfl(av, k);
            float hb = __shfl(hv, k);
            o += ab * WlT[k][lane] + hb * WrT[k][lane];
        }
        // LayerNorm across 64 lanes (biased variance, eps=1e-5)
        float mu = o;
        #pragma unroll
        for (int off = 32; off > 0; off >>= 1) mu += __shfl_xor(mu, off);
        mu *= (1.0f / 64.0f);
        float d0 = o - mu;
        float var = d0 * d0;
        #pragma unroll
        for (int off = 32; off > 0; off >>= 1) var += __shfl_xor(var, off);
        var *= (1.0f / 64.0f);
        float inv = rsqrtf(var + 1e-5f);
        out[(size_t)r * DIM + lane] = d0 * inv * gsh[lane] + bsh[lane];
    }
}

extern "C" void kernel_launch(void* const* d_in, const int* in_sizes, int n_in,
                              void* d_out, int out_size, void* d_ws, size_t ws_size,
                              hipStream_t stream)
{
    const float* x      = (const float*)d_in[0];
    const int*   ei     = (const int*)d_in[1];
    const float* W_proj = (const float*)d_in[2];
    const float* b_proj = (const float*)d_in[3];
    const float* W_l    = (const float*)d_in[4];
    const float* b_l    = (const float*)d_in[5];
    const float* W_r    = (const float*)d_in[6];
    const float* gamma  = (const float*)d_in[7];
    const float* beta   = (const float*)d_in[8];

    const int N = in_sizes[0] / DIM;
    const int E = in_sizes[1] / 2;
    const int L = in_sizes[2] / (DIM * DIM);

    const int* src  = ei;
    const int* dstp = ei + E;

    const int nblocks = (N + 255) / 256;

    float* hp        = (float*)d_ws;
    float* h1        = hp + (size_t)N * DIM;
    int*   degi      = (int*)(h1 + (size_t)N * DIM);
    int*   row_start = degi + N;
    int*   cursor    = row_start + N + 1;
    int*   csr_src   = cursor + N;
    int*   blockSums = csr_src + E;

    // ---- build CSR (once; shared by both layers) ----
    hipMemsetAsync(degi, 0, (size_t)N * sizeof(int), stream);
    hist_kernel<<<2048, 256, 0, stream>>>(dstp, degi, E);
    scanA_kernel<<<nblocks, 256, 0, stream>>>(degi, blockSums, N);
    scanB_kernel<<<1, 256, 0, stream>>>(blockSums, nblocks);
    scanC_kernel<<<nblocks, 256, 0, stream>>>(degi, blockSums, row_start, cursor, N);
    bucket_kernel<<<2048, 256, 0, stream>>>(src, dstp, cursor, csr_src, E);

    // ---- layers ----
    const float* hin = x;
    for (int l = 0; l < L; ++l) {
        proj_kernel<<<2048, 256, 0, stream>>>(hin, W_proj + (size_t)l * DIM * DIM,
                                              b_proj + (size_t)l * DIM, hp, N);
        float* outp = (l == L - 1) ? (float*)d_out : h1;
        agg_combine_ln_kernel<<<2048, 256, 0, stream>>>(hin, hp, row_start, csr_src,
                                                        W_l + (size_t)l * DIM * DIM, b_l + (size_t)l * DIM,
                                                        W_r + (size_t)l * DIM * DIM,
                                                        gamma + (size_t)l * DIM, beta + (size_t)l * DIM,
                                                        outp, N);
        hin = h1;
    }
}